// Round 7
// baseline (109.088 us; speedup 1.0000x reference)
//
#include <hip/hip_runtime.h>
#include <hip/hip_fp16.h>

// RoIAlign (legacy, grid spacing roi/(P-1), PH=PW=8, zero for OOR samples)
// fused with 2x2 stride-1 max-pool -> out [R, C=256, 7, 7] float32.
//
// R7: features channels-last f16 [B,H,W,C] (56 MB). Main kernel: one block
// per (roi, 128-channel half) -> 4000 blocks of 128 threads, ~13.9 KB LDS
// (12 blocks/CU). Thread = channel pair, 2 row-halves (9 row samples/roi),
// column-max on the fly. VGPR cap 102 (launch_bounds(128,5)) so the compiler
// can keep ~2 rows of independent gathers in flight (R6 was starved at 56).

#define FH 200
#define FW 272
#define FC 256
#define FHW (FH * FW)          // 54400
#define SPATIAL_SCALE 0.25f
#define PIX2 (FC / 2)          // pixel stride in half2 units: 128

// ---------------- transpose+convert [B,C,HW] f32 -> [B,HW,C] f16 ----------
__global__ __launch_bounds__(256) void transpose_f16_kernel(
    const float* __restrict__ in, __half* __restrict__ outT)
{
    __shared__ float tile[64][65];
    const int hw0  = blockIdx.x * 64;
    const int c0   = blockIdx.y * 64;
    const int b    = blockIdx.z;
    const int lane = threadIdx.x & 63;
    const int sub  = threadIdx.x >> 6;   // 0..3

    const float* inb = in + (size_t)b * FC * FHW;
    #pragma unroll
    for (int i = 0; i < 16; ++i) {
        const int c = sub * 16 + i;
        tile[c][lane] = inb[(size_t)(c0 + c) * FHW + hw0 + lane];
    }
    __syncthreads();
    __half* outb = outT + (size_t)b * FHW * FC;
    #pragma unroll
    for (int i = 0; i < 16; ++i) {
        const int hw = sub * 16 + i;
        outb[(size_t)(hw0 + hw) * FC + c0 + lane] = __float2half(tile[lane][hw]);
    }
}

// ---------------- main: f16 channels-last gather + fused pool -------------
__global__ __launch_bounds__(128, 5) void roi_align_max_f16h_kernel(
    const __half2* __restrict__ featT,  // [B, H, W, C/2] half2
    const float* __restrict__ rois,     // [R, 5]
    float* __restrict__ out,            // [R, C, 7, 7]
    int R)
{
    __shared__ int    s_off[64];         // (y0*W + x0) * PIX2 (half2 units)
    __shared__ float  s_w0[64], s_w1[64], s_w2[64], s_w3[64];
    __shared__ int    s_base;            // b * H*W*PIX2
    __shared__ __half s_out16[128 * 49]; // 12.25 KB pooled-output staging

    const int r   = blockIdx.x;
    const int ch  = blockIdx.y;          // channel half: pairs [64ch, 64ch+63]
    const int tid = threadIdx.x;

    if (tid < 64) {
        const float b  = rois[r * 5 + 0];
        const float x1 = rois[r * 5 + 1] * SPATIAL_SCALE;
        const float y1 = rois[r * 5 + 2] * SPATIAL_SCALE;
        const float x2 = rois[r * 5 + 3] * SPATIAL_SCALE;
        const float y2 = rois[r * 5 + 4] * SPATIAL_SCALE;
        const float bin_h = fmaxf(y2 - y1, 0.0f) * (1.0f / 7.0f);
        const float bin_w = fmaxf(x2 - x1, 0.0f) * (1.0f / 7.0f);

        const int ph = tid >> 3;
        const int pw = tid & 7;
        const float h = y1 + (float)ph * bin_h;
        const float w = x1 + (float)pw * bin_w;

        const bool valid = (h >= 0.0f) && (h < (float)FH) &&
                           (w >= 0.0f) && (w < (float)FW);
        // legacy: clip floor() into [0, H-2]; fractions NOT re-clamped
        const float h0 = fminf(fmaxf(floorf(h), 0.0f), (float)(FH - 2));
        const float w0 = fminf(fmaxf(floorf(w), 0.0f), (float)(FW - 2));
        const float fh = h - h0;
        const float fw = w - w0;
        const float v  = valid ? 1.0f : 0.0f;

        s_off[tid] = ((int)h0 * FW + (int)w0) * PIX2;
        s_w0[tid] = (1.0f - fh) * (1.0f - fw) * v;
        s_w1[tid] = (1.0f - fh) * fw * v;
        s_w2[tid] = fh * (1.0f - fw) * v;
        s_w3[tid] = fh * fw * v;
        if (tid == 0) s_base = (int)b * (FHW * PIX2);
    }
    __syncthreads();

    const int cp   = tid & 63;    // local channel pair (0..63)
    const int half = tid >> 6;    // 0: aligned rows 0..3 ; 1: rows 3..7
    const __half2* __restrict__ f = featT + s_base + ch * 64 + cp;

    const int row0 = (half == 0) ? 0 : 3;
    const int nout = (half == 0) ? 3 : 4;

    // sample one aligned row and reduce to column-max cm[7] on the fly
    auto sample_cm = [&](int ar, float2* cm) {
        float2 vp;
        #pragma unroll
        for (int pw = 0; pw < 8; ++pw) {
            const int m = ar * 8 + pw;
            const int o = s_off[m];
            const float2 a00 = __half22float2(f[o]);
            const float2 a01 = __half22float2(f[o + PIX2]);
            const float2 a10 = __half22float2(f[o + FW * PIX2]);
            const float2 a11 = __half22float2(f[o + FW * PIX2 + PIX2]);
            const float w0v = s_w0[m], w1v = s_w1[m];
            const float w2v = s_w2[m], w3v = s_w3[m];
            float2 v;
            v.x = a00.x * w0v + a01.x * w1v + a10.x * w2v + a11.x * w3v;
            v.y = a00.y * w0v + a01.y * w1v + a10.y * w2v + a11.y * w3v;
            if (pw > 0) {
                cm[pw - 1].x = fmaxf(vp.x, v.x);
                cm[pw - 1].y = fmaxf(vp.y, v.y);
            }
            vp = v;
        }
    };

    float2 cmp_[7];
    sample_cm(row0, cmp_);
    for (int j = 0; j < nout; ++j) {
        float2 cmc[7];
        sample_cm(row0 + 1 + j, cmc);
        const int oh7 = (row0 + j) * 7;
        #pragma unroll
        for (int ow = 0; ow < 7; ++ow) {
            s_out16[(2 * cp)     * 49 + oh7 + ow] =
                __float2half(fmaxf(cmp_[ow].x, cmc[ow].x));
            s_out16[(2 * cp + 1) * 49 + oh7 + ow] =
                __float2half(fmaxf(cmp_[ow].y, cmc[ow].y));
        }
        #pragma unroll
        for (int ow = 0; ow < 7; ++ow) cmp_[ow] = cmc[ow];
    }
    __syncthreads();

    // dense float4 writeout (f16 -> f32) of this half-roi's [128,7,7] slab
    float4* o4 = (float4*)(out + (size_t)r * (FC * 49) + ch * (128 * 49));
    #pragma unroll
    for (int k = 0; k < 13; ++k) {
        const int idx = k * 128 + tid;        // group of 4 halves
        if (idx < (128 * 49 / 4)) {
            const __half2* sh2 = (const __half2*)(s_out16 + idx * 4);
            const float2 lo = __half22float2(sh2[0]);
            const float2 hi = __half22float2(sh2[1]);
            o4[idx] = make_float4(lo.x, lo.y, hi.x, hi.y);
        }
    }
}

// ---------------- fallback (NCHW direct) if ws too small ------------------
__global__ __launch_bounds__(256) void roi_align_max_kernel(
    const float* __restrict__ feat, const float* __restrict__ rois,
    float* __restrict__ out, int R)
{
    __shared__ int   s_off[64];
    __shared__ float s_w0[64], s_w1[64], s_w2[64], s_w3[64];
    __shared__ int   s_base;

    const int r   = blockIdx.x;
    const int tid = threadIdx.x;

    if (tid < 64) {
        const float b  = rois[r * 5 + 0];
        const float x1 = rois[r * 5 + 1] * SPATIAL_SCALE;
        const float y1 = rois[r * 5 + 2] * SPATIAL_SCALE;
        const float x2 = rois[r * 5 + 3] * SPATIAL_SCALE;
        const float y2 = rois[r * 5 + 4] * SPATIAL_SCALE;
        const float bin_h = fmaxf(y2 - y1, 0.0f) * (1.0f / 7.0f);
        const float bin_w = fmaxf(x2 - x1, 0.0f) * (1.0f / 7.0f);
        const int ph = tid >> 3;
        const int pw = tid & 7;
        const float h = y1 + (float)ph * bin_h;
        const float w = x1 + (float)pw * bin_w;
        const bool valid = (h >= 0.0f) && (h < (float)FH) &&
                           (w >= 0.0f) && (w < (float)FW);
        const float h0 = fminf(fmaxf(floorf(h), 0.0f), (float)(FH - 2));
        const float w0 = fminf(fmaxf(floorf(w), 0.0f), (float)(FW - 2));
        const float fh = h - h0;
        const float fw = w - w0;
        const float v  = valid ? 1.0f : 0.0f;
        s_off[tid] = (int)h0 * FW + (int)w0;
        s_w0[tid] = (1.0f - fh) * (1.0f - fw) * v;
        s_w1[tid] = (1.0f - fh) * fw * v;
        s_w2[tid] = fh * (1.0f - fw) * v;
        s_w3[tid] = fh * fw * v;
        if (tid == 0) s_base = (int)b * (FC * FHW);
    }
    __syncthreads();

    const int c = tid;
    const float* __restrict__ f = feat + s_base + c * FHW;
    float* __restrict__ outp = out + ((size_t)r * FC + c) * 49;

    float prev[8];
    for (int ph = 0; ph < 8; ++ph) {
        float cur[8];
        #pragma unroll
        for (int pw = 0; pw < 8; ++pw) {
            const int m = ph * 8 + pw;
            const int o = s_off[m];
            cur[pw] = f[o] * s_w0[m] + f[o + 1] * s_w1[m]
                    + f[o + FW] * s_w2[m] + f[o + FW + 1] * s_w3[m];
        }
        if (ph > 0) {
            #pragma unroll
            for (int ow = 0; ow < 7; ++ow)
                outp[(ph - 1) * 7 + ow] =
                    fmaxf(fmaxf(prev[ow], prev[ow + 1]),
                          fmaxf(cur[ow],  cur[ow + 1]));
        }
        #pragma unroll
        for (int pw = 0; pw < 8; ++pw) prev[pw] = cur[pw];
    }
}

extern "C" void kernel_launch(void* const* d_in, const int* in_sizes, int n_in,
                              void* d_out, int out_size, void* d_ws, size_t ws_size,
                              hipStream_t stream) {
    const float* feat = (const float*)d_in[0];
    const float* rois = (const float*)d_in[1];
    float* out = (float*)d_out;
    const int R = in_sizes[1] / 5;
    if (R <= 0) return;

    const size_t needed = (size_t)2 * FC * FHW * sizeof(__half);  // 55.7 MB
    if (ws_size >= needed) {
        __half* featT = (__half*)d_ws;
        transpose_f16_kernel<<<dim3(FHW / 64, FC / 64, 2), 256, 0, stream>>>(feat, featT);
        roi_align_max_f16h_kernel<<<dim3(R, 2), 128, 0, stream>>>(
            (const __half2*)featT, rois, out, R);
    } else {
        roi_align_max_kernel<<<R, 256, 0, stream>>>(feat, rois, out, R);
    }
}

// Round 8
// 108.272 us; speedup vs baseline: 1.0075x; 1.0075x over previous
//
#include <hip/hip_runtime.h>
#include <hip/hip_fp16.h>

// RoIAlign (legacy, grid spacing roi/(P-1), PH=PW=8, zero for OOR samples)
// fused with 2x2 stride-1 max-pool -> out [R, C=256, 7, 7] float32.
//
// R8: features channels-last f16 [B,H,W,C] (56 MB). Block = roi (256 thr),
// thread = channel pair, 2 row-halves (9 row samples/roi), column-max.
// KEY CHANGE vs R6: each sampled row's 32 gather loads are batched into
// register arrays BEFORE any use -> 32-deep MLP per wave (R6's consume-
// immediately chain left the memory pipe idle; VALUBusy was 21%).
// launch_bounds(256,5): VGPR cap 102, need ~75, no spill (R5 lesson).

#define FH 200
#define FW 272
#define FC 256
#define FHW (FH * FW)          // 54400
#define SPATIAL_SCALE 0.25f
#define PIX2 (FC / 2)          // pixel stride in half2 units: 128

// ---------------- transpose+convert [B,C,HW] f32 -> [B,HW,C] f16 ----------
__global__ __launch_bounds__(256) void transpose_f16_kernel(
    const float* __restrict__ in, __half* __restrict__ outT)
{
    __shared__ float tile[64][65];
    const int hw0  = blockIdx.x * 64;
    const int c0   = blockIdx.y * 64;
    const int b    = blockIdx.z;
    const int lane = threadIdx.x & 63;
    const int sub  = threadIdx.x >> 6;   // 0..3

    const float* inb = in + (size_t)b * FC * FHW;
    #pragma unroll
    for (int i = 0; i < 16; ++i) {
        const int c = sub * 16 + i;
        tile[c][lane] = inb[(size_t)(c0 + c) * FHW + hw0 + lane];
    }
    __syncthreads();
    __half* outb = outT + (size_t)b * FHW * FC;
    #pragma unroll
    for (int i = 0; i < 16; ++i) {
        const int hw = sub * 16 + i;
        outb[(size_t)(hw0 + hw) * FC + c0 + lane] = __float2half(tile[lane][hw]);
    }
}

// ---------------- main: f16 channels-last gather + fused pool -------------
__global__ __launch_bounds__(256, 5) void roi_align_max_f16b_kernel(
    const __half2* __restrict__ featT,  // [B, H, W, C/2] half2
    const float* __restrict__ rois,     // [R, 5]
    float* __restrict__ out,            // [R, C, 7, 7]
    int R)
{
    __shared__ int    s_off[64];         // (y0*W + x0) * PIX2 (half2 units)
    __shared__ float  s_w0[64], s_w1[64], s_w2[64], s_w3[64];
    __shared__ int    s_base;            // b * H*W*PIX2
    __shared__ __half s_out16[FC * 49];  // 24.5 KB pooled-output staging

    const int r   = blockIdx.x;
    const int tid = threadIdx.x;

    if (tid < 64) {
        const float b  = rois[r * 5 + 0];
        const float x1 = rois[r * 5 + 1] * SPATIAL_SCALE;
        const float y1 = rois[r * 5 + 2] * SPATIAL_SCALE;
        const float x2 = rois[r * 5 + 3] * SPATIAL_SCALE;
        const float y2 = rois[r * 5 + 4] * SPATIAL_SCALE;
        const float bin_h = fmaxf(y2 - y1, 0.0f) * (1.0f / 7.0f);
        const float bin_w = fmaxf(x2 - x1, 0.0f) * (1.0f / 7.0f);

        const int ph = tid >> 3;
        const int pw = tid & 7;
        const float h = y1 + (float)ph * bin_h;
        const float w = x1 + (float)pw * bin_w;

        const bool valid = (h >= 0.0f) && (h < (float)FH) &&
                           (w >= 0.0f) && (w < (float)FW);
        // legacy: clip floor() into [0, H-2]; fractions NOT re-clamped
        const float h0 = fminf(fmaxf(floorf(h), 0.0f), (float)(FH - 2));
        const float w0 = fminf(fmaxf(floorf(w), 0.0f), (float)(FW - 2));
        const float fh = h - h0;
        const float fw = w - w0;
        const float v  = valid ? 1.0f : 0.0f;

        s_off[tid] = ((int)h0 * FW + (int)w0) * PIX2;
        s_w0[tid] = (1.0f - fh) * (1.0f - fw) * v;
        s_w1[tid] = (1.0f - fh) * fw * v;
        s_w2[tid] = fh * (1.0f - fw) * v;
        s_w3[tid] = fh * fw * v;
        if (tid == 0) s_base = (int)b * (FHW * PIX2);
    }
    __syncthreads();

    const int cp   = tid & 127;   // channel pair: channels 2cp, 2cp+1
    const int half = tid >> 7;    // 0: aligned rows 0..3 ; 1: rows 3..7
    const __half2* __restrict__ f = featT + s_base + cp;

    const int row0 = (half == 0) ? 0 : 3;
    const int nout = (half == 0) ? 3 : 4;

    // sample one aligned row: BATCH all 32 loads first (32-deep MLP), then
    // convert+combine and reduce to column-max cm[7].
    auto sample_cm = [&](int ar, float2* cm) {
        __half2 h00[8], h01[8], h10[8], h11[8];
        #pragma unroll
        for (int pw = 0; pw < 8; ++pw) {
            const int o = s_off[ar * 8 + pw];
            h00[pw] = f[o];
            h01[pw] = f[o + PIX2];
            h10[pw] = f[o + FW * PIX2];
            h11[pw] = f[o + FW * PIX2 + PIX2];
        }
        float2 vp;
        #pragma unroll
        for (int pw = 0; pw < 8; ++pw) {
            const int m = ar * 8 + pw;
            const float2 a00 = __half22float2(h00[pw]);
            const float2 a01 = __half22float2(h01[pw]);
            const float2 a10 = __half22float2(h10[pw]);
            const float2 a11 = __half22float2(h11[pw]);
            const float w0v = s_w0[m], w1v = s_w1[m];
            const float w2v = s_w2[m], w3v = s_w3[m];
            float2 v;
            v.x = a00.x * w0v + a01.x * w1v + a10.x * w2v + a11.x * w3v;
            v.y = a00.y * w0v + a01.y * w1v + a10.y * w2v + a11.y * w3v;
            if (pw > 0) {
                cm[pw - 1].x = fmaxf(vp.x, v.x);
                cm[pw - 1].y = fmaxf(vp.y, v.y);
            }
            vp = v;
        }
    };

    float2 cmp_[7];
    sample_cm(row0, cmp_);
    for (int j = 0; j < nout; ++j) {
        float2 cmc[7];
        sample_cm(row0 + 1 + j, cmc);
        const int oh7 = (row0 + j) * 7;
        #pragma unroll
        for (int ow = 0; ow < 7; ++ow) {
            s_out16[(2 * cp)     * 49 + oh7 + ow] =
                __float2half(fmaxf(cmp_[ow].x, cmc[ow].x));
            s_out16[(2 * cp + 1) * 49 + oh7 + ow] =
                __float2half(fmaxf(cmp_[ow].y, cmc[ow].y));
        }
        #pragma unroll
        for (int ow = 0; ow < 7; ++ow) cmp_[ow] = cmc[ow];
    }
    __syncthreads();

    // dense float4 writeout (f16 -> f32) of this roi's [C,7,7] slab
    float4* o4 = (float4*)(out + (size_t)r * (FC * 49));
    #pragma unroll
    for (int k = 0; k < 13; ++k) {
        const int idx = k * 256 + tid;        // group of 4 halves
        if (idx < (FC * 49 / 4)) {
            const __half2* sh2 = (const __half2*)(s_out16 + idx * 4);
            const float2 lo = __half22float2(sh2[0]);
            const float2 hi = __half22float2(sh2[1]);
            o4[idx] = make_float4(lo.x, lo.y, hi.x, hi.y);
        }
    }
}

// ---------------- fallback (NCHW direct) if ws too small ------------------
__global__ __launch_bounds__(256) void roi_align_max_kernel(
    const float* __restrict__ feat, const float* __restrict__ rois,
    float* __restrict__ out, int R)
{
    __shared__ int   s_off[64];
    __shared__ float s_w0[64], s_w1[64], s_w2[64], s_w3[64];
    __shared__ int   s_base;

    const int r   = blockIdx.x;
    const int tid = threadIdx.x;

    if (tid < 64) {
        const float b  = rois[r * 5 + 0];
        const float x1 = rois[r * 5 + 1] * SPATIAL_SCALE;
        const float y1 = rois[r * 5 + 2] * SPATIAL_SCALE;
        const float x2 = rois[r * 5 + 3] * SPATIAL_SCALE;
        const float y2 = rois[r * 5 + 4] * SPATIAL_SCALE;
        const float bin_h = fmaxf(y2 - y1, 0.0f) * (1.0f / 7.0f);
        const float bin_w = fmaxf(x2 - x1, 0.0f) * (1.0f / 7.0f);
        const int ph = tid >> 3;
        const int pw = tid & 7;
        const float h = y1 + (float)ph * bin_h;
        const float w = x1 + (float)pw * bin_w;
        const bool valid = (h >= 0.0f) && (h < (float)FH) &&
                           (w >= 0.0f) && (w < (float)FW);
        const float h0 = fminf(fmaxf(floorf(h), 0.0f), (float)(FH - 2));
        const float w0 = fminf(fmaxf(floorf(w), 0.0f), (float)(FW - 2));
        const float fh = h - h0;
        const float fw = w - w0;
        const float v  = valid ? 1.0f : 0.0f;
        s_off[tid] = (int)h0 * FW + (int)w0;
        s_w0[tid] = (1.0f - fh) * (1.0f - fw) * v;
        s_w1[tid] = (1.0f - fh) * fw * v;
        s_w2[tid] = fh * (1.0f - fw) * v;
        s_w3[tid] = fh * fw * v;
        if (tid == 0) s_base = (int)b * (FC * FHW);
    }
    __syncthreads();

    const int c = tid;
    const float* __restrict__ f = feat + s_base + c * FHW;
    float* __restrict__ outp = out + ((size_t)r * FC + c) * 49;

    float prev[8];
    for (int ph = 0; ph < 8; ++ph) {
        float cur[8];
        #pragma unroll
        for (int pw = 0; pw < 8; ++pw) {
            const int m = ph * 8 + pw;
            const int o = s_off[m];
            cur[pw] = f[o] * s_w0[m] + f[o + 1] * s_w1[m]
                    + f[o + FW] * s_w2[m] + f[o + FW + 1] * s_w3[m];
        }
        if (ph > 0) {
            #pragma unroll
            for (int ow = 0; ow < 7; ++ow)
                outp[(ph - 1) * 7 + ow] =
                    fmaxf(fmaxf(prev[ow], prev[ow + 1]),
                          fmaxf(cur[ow],  cur[ow + 1]));
        }
        #pragma unroll
        for (int pw = 0; pw < 8; ++pw) prev[pw] = cur[pw];
    }
}

extern "C" void kernel_launch(void* const* d_in, const int* in_sizes, int n_in,
                              void* d_out, int out_size, void* d_ws, size_t ws_size,
                              hipStream_t stream) {
    const float* feat = (const float*)d_in[0];
    const float* rois = (const float*)d_in[1];
    float* out = (float*)d_out;
    const int R = in_sizes[1] / 5;
    if (R <= 0) return;

    const size_t needed = (size_t)2 * FC * FHW * sizeof(__half);  // 55.7 MB
    if (ws_size >= needed) {
        __half* featT = (__half*)d_ws;
        transpose_f16_kernel<<<dim3(FHW / 64, FC / 64, 2), 256, 0, stream>>>(feat, featT);
        roi_align_max_f16b_kernel<<<R, 256, 0, stream>>>(
            (const __half2*)featT, rois, out, R);
    } else {
        roi_align_max_kernel<<<R, 256, 0, stream>>>(feat, rois, out, R);
    }
}

// Round 9
// 79.995 us; speedup vs baseline: 1.3637x; 1.3535x over previous
//
#include <hip/hip_runtime.h>
#include <hip/hip_fp16.h>

// RoIAlign (legacy, grid spacing roi/(P-1), PH=PW=8, zero for OOR samples)
// fused with 2x2 stride-1 max-pool -> out [R, C=256, 7, 7] float32.
//
// R9: features channels-last f16 [B,H,W,C]. Main kernel uses
// global_load_lds DMA (VGPR-free MLP; R5/R7/R8 showed hipcc spills any
// register-based batching >~60 VGPR). Per aligned row, 16 x 1KB chunks
// (8 points x 2 feature rows; corner cols x0,x0+1 are contiguous 1KB).
// Triple-buffered rows, raw s_barrier + counted vmcnt(4) (never drain
// mid-loop), issue-after-compute. 512 persistent blocks (2/CU), grid-stride
// over rois to remove the scheduling-generation tail.

#define FH 200
#define FW 272
#define FC 256
#define FHW (FH * FW)          // 54400
#define SPATIAL_SCALE 0.25f
#define RECB 512               // bytes per pixel record (256 ch * 2 B)
#define ROWB (FW * RECB)       // bytes per feature row
#define NBLK 512               // persistent grid (2 blocks/CU * 256 CU)

// ---------------- transpose+convert [B,C,HW] f32 -> [B,HW,C] f16 ----------
__global__ __launch_bounds__(256) void transpose_f16_kernel(
    const float* __restrict__ in, __half* __restrict__ outT)
{
    __shared__ float tile[64][65];
    const int hw0  = blockIdx.x * 64;
    const int c0   = blockIdx.y * 64;
    const int b    = blockIdx.z;
    const int lane = threadIdx.x & 63;
    const int sub  = threadIdx.x >> 6;   // 0..3

    const float* inb = in + (size_t)b * FC * FHW;
    #pragma unroll
    for (int i = 0; i < 16; ++i) {
        const int c = sub * 16 + i;
        tile[c][lane] = inb[(size_t)(c0 + c) * FHW + hw0 + lane];
    }
    __syncthreads();
    __half* outb = outT + (size_t)b * FHW * FC;
    #pragma unroll
    for (int i = 0; i < 16; ++i) {
        const int hw = sub * 16 + i;
        outb[(size_t)(hw0 + hw) * FC + c0 + lane] = __float2half(tile[lane][hw]);
    }
}

// ---------------- main: DMA-staged gather + fused pool --------------------
__global__ __launch_bounds__(256, 2) void roi_align_max_dma_kernel(
    const __half* __restrict__ featT,   // [B, H, W, C] f16
    const float* __restrict__ rois,     // [R, 5]
    float* __restrict__ out,            // [R, C, 7, 7]
    int R)
{
    __shared__ int      s_boff[64];         // record byte offset per grid pt
    __shared__ float    s_w0[64], s_w1[64], s_w2[64], s_w3[64];
    __shared__ uint32_t s_buf[3][4096];     // 3 x 16 KB row staging
    __shared__ __half   s_out16[FC * 49];   // 24.5 KB pooled output

    const int tid  = threadIdx.x;
    const int lane = tid & 63;
    const int wid  = tid >> 6;     // wave 0..3
    const int cp   = tid & 127;    // channel pair: channels 2cp, 2cp+1
    const int h    = tid >> 7;     // pw-half: 0 -> pw 0..3, 1 -> pw 3..7
    const char* fbytes = (const char*)featT;

    // issue one aligned row's 16 x 1KB chunks (4 per wave) via DMA
    auto issue_row = [&](int row) {
        const int rm  = row * 8;
        const int bsel = row % 3;
        #pragma unroll
        for (int i = 0; i < 4; ++i) {
            const int q  = wid * 4 + i;     // chunk 0..15
            const int fr = q >> 3;          // feature row 0/1
            const int pw = q & 7;           // grid col
            const char* g = fbytes + s_boff[rm + pw] + fr * ROWB + lane * 16;
            __builtin_amdgcn_global_load_lds(
                (const uint32_t*)g, &s_buf[bsel][q * 256], 16, 0, 0);
        }
    };

    for (int r = blockIdx.x; r < R; r += NBLK) {
        // ---- per-roi setup (64 grid points) ----
        if (tid < 64) {
            const float b  = rois[r * 5 + 0];
            const float x1 = rois[r * 5 + 1] * SPATIAL_SCALE;
            const float y1 = rois[r * 5 + 2] * SPATIAL_SCALE;
            const float x2 = rois[r * 5 + 3] * SPATIAL_SCALE;
            const float y2 = rois[r * 5 + 4] * SPATIAL_SCALE;
            const float bin_h = fmaxf(y2 - y1, 0.0f) * (1.0f / 7.0f);
            const float bin_w = fmaxf(x2 - x1, 0.0f) * (1.0f / 7.0f);

            const int ph = tid >> 3;
            const int pw = tid & 7;
            const float hh = y1 + (float)ph * bin_h;
            const float ww = x1 + (float)pw * bin_w;

            const bool valid = (hh >= 0.0f) && (hh < (float)FH) &&
                               (ww >= 0.0f) && (ww < (float)FW);
            // legacy: clip floor() into [0, H-2]; fractions NOT re-clamped
            const float h0 = fminf(fmaxf(floorf(hh), 0.0f), (float)(FH - 2));
            const float w0 = fminf(fmaxf(floorf(ww), 0.0f), (float)(FW - 2));
            const float fh = hh - h0;
            const float fw = ww - w0;
            const float v  = valid ? 1.0f : 0.0f;

            s_boff[tid] = ((int)b * FHW + (int)h0 * FW + (int)w0) * RECB;
            s_w0[tid] = (1.0f - fh) * (1.0f - fw) * v;
            s_w1[tid] = (1.0f - fh) * fw * v;
            s_w2[tid] = fh * (1.0f - fw) * v;
            s_w3[tid] = fh * fw * v;
        }
        __syncthreads();

        issue_row(0);
        issue_row(1);

        const int npt = h ? 5 : 4;      // points this half computes
        const int ncm = h ? 4 : 3;      // col-max outputs
        const int pw0 = h ? 3 : 0;
        const int owb = h ? 3 : 0;
        float2 prev[4];

        #pragma unroll
        for (int ar = 0; ar < 8; ++ar) {
            if (ar == 7) { asm volatile("s_waitcnt vmcnt(0)" ::: "memory"); }
            else         { asm volatile("s_waitcnt vmcnt(4)" ::: "memory"); }
            __builtin_amdgcn_sched_barrier(0);
            __builtin_amdgcn_s_barrier();

            // compute aligned row ar from staged LDS
            const __half2* bh2 = (const __half2*)s_buf[ar % 3];
            float2 v[5];
            #pragma unroll
            for (int k = 0; k < 5; ++k) {
                if (k < npt) {
                    const int pw = pw0 + k;
                    const int m  = ar * 8 + pw;
                    const float2 a00 = __half22float2(bh2[pw * 256 + cp]);
                    const float2 a01 = __half22float2(bh2[pw * 256 + 128 + cp]);
                    const float2 a10 = __half22float2(bh2[(8 + pw) * 256 + cp]);
                    const float2 a11 = __half22float2(bh2[(8 + pw) * 256 + 128 + cp]);
                    const float w0v = s_w0[m], w1v = s_w1[m];
                    const float w2v = s_w2[m], w3v = s_w3[m];
                    v[k].x = a00.x * w0v + a01.x * w1v + a10.x * w2v + a11.x * w3v;
                    v[k].y = a00.y * w0v + a01.y * w1v + a10.y * w2v + a11.y * w3v;
                }
            }
            float2 cur[4];
            #pragma unroll
            for (int j = 0; j < 4; ++j) {
                if (j < ncm) {
                    cur[j].x = fmaxf(v[j].x, v[j + 1].x);
                    cur[j].y = fmaxf(v[j].y, v[j + 1].y);
                }
            }
            if (ar > 0) {
                const int ob = (ar - 1) * 7 + owb;
                #pragma unroll
                for (int j = 0; j < 4; ++j) {
                    if (j < ncm) {
                        s_out16[(2 * cp)     * 49 + ob + j] =
                            __float2half(fmaxf(prev[j].x, cur[j].x));
                        s_out16[(2 * cp + 1) * 49 + ob + j] =
                            __float2half(fmaxf(prev[j].y, cur[j].y));
                    }
                }
            }
            #pragma unroll
            for (int j = 0; j < 4; ++j) prev[j] = cur[j];

            if (ar < 6) issue_row(ar + 2);
        }
        __syncthreads();

        // dense float4 writeout (f16 -> f32) of this roi's [C,7,7] slab
        float4* o4 = (float4*)(out + (size_t)r * (FC * 49));
        #pragma unroll
        for (int k = 0; k < 13; ++k) {
            const int idx = k * 256 + tid;      // group of 4 halves
            if (idx < (FC * 49 / 4)) {
                const __half2* sh2 = (const __half2*)(s_out16 + idx * 4);
                const float2 lo = __half22float2(sh2[0]);
                const float2 hi = __half22float2(sh2[1]);
                o4[idx] = make_float4(lo.x, lo.y, hi.x, hi.y);
            }
        }
        __syncthreads();   // s_out16/s_buf safe to reuse for next roi
    }
}

// ---------------- fallback (NCHW direct) if ws too small ------------------
__global__ __launch_bounds__(256) void roi_align_max_kernel(
    const float* __restrict__ feat, const float* __restrict__ rois,
    float* __restrict__ out, int R)
{
    __shared__ int   s_off[64];
    __shared__ float s_w0[64], s_w1[64], s_w2[64], s_w3[64];
    __shared__ int   s_base;

    const int r   = blockIdx.x;
    const int tid = threadIdx.x;

    if (tid < 64) {
        const float b  = rois[r * 5 + 0];
        const float x1 = rois[r * 5 + 1] * SPATIAL_SCALE;
        const float y1 = rois[r * 5 + 2] * SPATIAL_SCALE;
        const float x2 = rois[r * 5 + 3] * SPATIAL_SCALE;
        const float y2 = rois[r * 5 + 4] * SPATIAL_SCALE;
        const float bin_h = fmaxf(y2 - y1, 0.0f) * (1.0f / 7.0f);
        const float bin_w = fmaxf(x2 - x1, 0.0f) * (1.0f / 7.0f);
        const int ph = tid >> 3;
        const int pw = tid & 7;
        const float h = y1 + (float)ph * bin_h;
        const float w = x1 + (float)pw * bin_w;
        const bool valid = (h >= 0.0f) && (h < (float)FH) &&
                           (w >= 0.0f) && (w < (float)FW);
        const float h0 = fminf(fmaxf(floorf(h), 0.0f), (float)(FH - 2));
        const float w0 = fminf(fmaxf(floorf(w), 0.0f), (float)(FW - 2));
        const float fh = h - h0;
        const float fw = w - w0;
        const float v  = valid ? 1.0f : 0.0f;
        s_off[tid] = (int)h0 * FW + (int)w0;
        s_w0[tid] = (1.0f - fh) * (1.0f - fw) * v;
        s_w1[tid] = (1.0f - fh) * fw * v;
        s_w2[tid] = fh * (1.0f - fw) * v;
        s_w3[tid] = fh * fw * v;
        if (tid == 0) s_base = (int)b * (FC * FHW);
    }
    __syncthreads();

    const int c = tid;
    const float* __restrict__ f = feat + s_base + c * FHW;
    float* __restrict__ outp = out + ((size_t)r * FC + c) * 49;

    float prev[8];
    for (int ph = 0; ph < 8; ++ph) {
        float cur[8];
        #pragma unroll
        for (int pw = 0; pw < 8; ++pw) {
            const int m = ph * 8 + pw;
            const int o = s_off[m];
            cur[pw] = f[o] * s_w0[m] + f[o + 1] * s_w1[m]
                    + f[o + FW] * s_w2[m] + f[o + FW + 1] * s_w3[m];
        }
        if (ph > 0) {
            #pragma unroll
            for (int ow = 0; ow < 7; ++ow)
                outp[(ph - 1) * 7 + ow] =
                    fmaxf(fmaxf(prev[ow], prev[ow + 1]),
                          fmaxf(cur[ow],  cur[ow + 1]));
        }
        #pragma unroll
        for (int pw = 0; pw < 8; ++pw) prev[pw] = cur[pw];
    }
}

extern "C" void kernel_launch(void* const* d_in, const int* in_sizes, int n_in,
                              void* d_out, int out_size, void* d_ws, size_t ws_size,
                              hipStream_t stream) {
    const float* feat = (const float*)d_in[0];
    const float* rois = (const float*)d_in[1];
    float* out = (float*)d_out;
    const int R = in_sizes[1] / 5;
    if (R <= 0) return;

    const size_t needed = (size_t)2 * FC * FHW * sizeof(__half);  // 55.7 MB
    if (ws_size >= needed) {
        __half* featT = (__half*)d_ws;
        transpose_f16_kernel<<<dim3(FHW / 64, FC / 64, 2), 256, 0, stream>>>(feat, featT);
        const int nblk = (R < NBLK) ? R : NBLK;
        roi_align_max_dma_kernel<<<nblk, 256, 0, stream>>>(featT, rois, out, R);
    } else {
        roi_align_max_kernel<<<R, 256, 0, stream>>>(feat, rois, out, R);
    }
}